// Round 5
// baseline (1329.353 us; speedup 1.0000x reference)
//
#include <hip/hip_runtime.h>
#include <stdint.h>
#include <stddef.h>

typedef unsigned short u16t;
typedef unsigned int   u32t;
typedef __bf16  bf16x8 __attribute__((ext_vector_type(8)));
typedef float   f32x4  __attribute__((ext_vector_type(4)));
typedef u32t    u32x4  __attribute__((ext_vector_type(4)));

#define NN 50000
#define NE 800000
#define NG 16
#define DD 64
#define HH 128

#define AS 200   // edge A-tile row stride (u16): 192 + 8 pad -> 2-way bank alias (free)
#define HS 136   // h-tile row stride (u16): 128 + 8
#define EAS 72   // sEagg row stride (f32)
#define NS 136   // node A-tile row stride (u16): 128 + 8

static __device__ __forceinline__ float bf2f(u16t h){
  return __uint_as_float(((u32t)h) << 16);
}
static __device__ __forceinline__ u16t f2bf(float f){
  u32t u = __float_as_uint(f);
  u32t r = u + 0x7FFFu + ((u >> 16) & 1u);   // RNE
  return (u16t)(r >> 16);
}
static __device__ __forceinline__ u32t pk2(float lo, float hi){
  return ((u32t)f2bf(hi) << 16) | (u32t)f2bf(lo);
}
static __device__ __forceinline__ bf16x8 ldfrag(const u16t* p){
  return __builtin_bit_cast(bf16x8, *(const uint4*)p);
}
// runtime-dtype helpers (small kernels)
static __device__ __forceinline__ float ldb(const void* b, int i, bool f32){
  return f32 ? ((const float*)b)[i] : bf2f(((const u16t*)b)[i]);
}
static __device__ __forceinline__ void store1nt_rt(void* out, size_t idx, float v, bool f32){
  if (f32) __builtin_nontemporal_store(v, (float*)out + idx);
  else     __builtin_nontemporal_store(f2bf(v), (u16t*)out + idx);
}
// templated helpers (edge kernel)
template<bool F32>
static __device__ __forceinline__ float ldbT(const void* b, int i){
  return F32 ? ((const float*)b)[i] : bf2f(((const u16t*)b)[i]);
}
template<bool F32>
static __device__ __forceinline__ void store1nt(void* out, size_t idx, float v){
  if (F32) __builtin_nontemporal_store(v, (float*)out + idx);
  else     __builtin_nontemporal_store(f2bf(v), (u16t*)out + idx);
}
// stage 16 consecutive logical elements -> 16 bf16 in LDS via 2x ds_write_b128
static __device__ __forceinline__ void stage16(u16t* dst, const void* src, size_t eoff, bool f32){
  if (!f32){
    const u16t* p = (const u16t*)src + eoff;
    *(uint4*)(dst)     = *(const uint4*)(p);
    *(uint4*)(dst + 8) = *(const uint4*)(p + 8);
  } else {
    const float* p = (const float*)src + eoff;
    float4 a = *(const float4*)(p);
    float4 b = *(const float4*)(p + 4);
    float4 c = *(const float4*)(p + 8);
    float4 d = *(const float4*)(p + 12);
    uint4 o0 = { pk2(a.x, a.y), pk2(a.z, a.w), pk2(b.x, b.y), pk2(b.z, b.w) };
    uint4 o1 = { pk2(c.x, c.y), pk2(c.z, c.w), pk2(d.x, d.y), pk2(d.z, d.w) };
    *(uint4*)(dst)     = o0;
    *(uint4*)(dst + 8) = o1;
  }
}

// Decide fp32 vs bf16 by interpreting x's first 256 u16 as bf16:
// true-bf16 N(0,1) data -> ~0 implausible; fp32 data -> ~45% implausible.
__global__ void detect_kernel(const void* x, int* flag){
  if (threadIdx.x == 0 && blockIdx.x == 0){
    const u16t* xh = (const u16t*)x;
    int bad = 0;
    for (int i = 0; i < 256; ++i){
      float a = fabsf(bf2f(xh[i]));
      if (!(a > 1e-6f && a < 1e4f)) bad++;   // NaN also lands here
    }
    *flag = (bad > 32) ? 1 : 0;   // 1 = inputs are fp32
  }
}

// Repack W[K][Ncols] into MFMA-B-fragment order (bf16):
// Wp[((kk*Ncols + n)*32) + t] = W[kk*32 + t][n], t = quad*8 + j.
__global__ void repack_kernel(const void* __restrict__ W, u16t* __restrict__ Wp,
                              int K, int Ncols, const int* __restrict__ flag){
  const bool f32 = (*flag != 0);
  int idx = blockIdx.x * 256 + threadIdx.x;
  if (idx >= K * Ncols) return;
  int per = Ncols * 32;
  int kk  = idx / per;
  int rem = idx - kk * per;
  int n   = rem >> 5;
  int t   = rem & 31;
  int src = (kk * 32 + t) * Ncols + n;
  float v = f32 ? ((const float*)W)[src] : bf2f(((const u16t*)W)[src]);
  Wp[idx] = f2bf(v);
}

// Fold the u-part of each MLP-1 into a per-graph bias row (fp32, exact):
// U1[g][c]  = be1[c] + sum_k u[g][k]*We1[192+k][c]   (likewise UA1, UN1)
__global__ void ufold_kernel(const void* __restrict__ u,
                             const void* __restrict__ We1, const void* __restrict__ be1,
                             const void* __restrict__ Wa1, const void* __restrict__ ba1,
                             const void* __restrict__ Wn1, const void* __restrict__ bn1,
                             float* __restrict__ U1, float* __restrict__ UA1,
                             float* __restrict__ UN1, const int* __restrict__ flag)
{
  const bool f32 = (*flag != 0);
  int idx = blockIdx.x * 256 + threadIdx.x;
  if (idx >= 3 * NG * HH) return;
  int which = idx / (NG * HH);
  int rem = idx - which * (NG * HH);
  int g = rem >> 7, c = rem & 127;
  const void* W; const void* b; int rowoff; float* out;
  if (which == 0)      { W = We1; b = be1; rowoff = 192; out = U1;  }
  else if (which == 1) { W = Wa1; b = ba1; rowoff = 192; out = UA1; }
  else                 { W = Wn1; b = bn1; rowoff = 128; out = UN1; }
  float sacc = ldb(b, c, f32);
  for (int k = 0; k < DD; ++k)
    sacc += ldb(u, g * DD + k, f32) * ldb(W, (rowoff + k) * HH + c, f32);
  out[rem] = sacc;
}

// Block-wide 64-edge tiles. Per-wave column slices of weights. u folded into
// U1/UA1. T14 pipeline: tile t+1's gathers issue right after tile t's staging
// commit; nt loads/stores keep the e / e_new streams out of L2/L3 so the
// per-tile weight re-reads stay cache-resident.
// Dual-instantiation dispatch: BOTH <true> and <false> get launched; the one
// whose F32 mismatches the device-detected flag exits immediately.
template<bool F32>
__global__ __launch_bounds__(256, 3) void edge_kernel(
  const void* __restrict__ x_, const int* __restrict__ ei, const void* __restrict__ e_,
  const int* __restrict__ batch,
  const u16t* __restrict__ Wp1, const u16t* __restrict__ WpA1,
  const u16t* __restrict__ Wp2, const void* __restrict__ b2,
  const u16t* __restrict__ WpA2, const void* __restrict__ ba2,
  const float* __restrict__ U1, const float* __restrict__ UA1,
  void* __restrict__ d_out, float* __restrict__ agg, float* __restrict__ edge_agg,
  const int* __restrict__ flag, int ntiles)
{
  if ((*flag != 0) != F32) return;   // wrong-dtype instantiation: no-op

  __shared__ u16t  sA[64 * AS];       // [xs | xd | e] 64 x 192
  __shared__ u16t  sH[64 * HS];
  __shared__ float sEagg[NG * EAS];
  __shared__ int   sDst[64];
  __shared__ int   sG[64];

  const size_t OUT_E = (size_t)NN * DD;

  const int tid  = threadIdx.x;
  const int wave = tid >> 6;
  const int lane = tid & 63;
  const int l15  = lane & 15;
  const int quad = lane >> 4;
  const int el   = tid >> 2;   // local edge 0..63 (4 threads/edge)
  const int q    = tid & 3;    // 16-col chunk within D=64

  for (int i = tid; i < NG * EAS; i += 256) sEagg[i] = 0.f;

  const int colbase = wave * 32;  // layer-1 col range per wave
  const int n0      = wave * 16;  // layer-2 col range per wave
  const float bias2  = ldbT<F32>(b2,  n0 + l15);
  const float biasA2 = ldbT<F32>(ba2, n0 + l15);

  const f32x4 vzero = {0.f, 0.f, 0.f, 0.f};

  // ---- T14 prefetch registers (one tile ahead) ----
  int   pD, pG;
  f32x4 pf[12];   // F32 path: 3 sources x 4
  u32x4 pb[6];    // bf16 path: 3 sources x 2

  auto issue = [&](int tile){
    const int eidx = tile * 64 + el;
    const int s = ei[eidx];
    pD = ei[NE + eidx];
    pG = batch[s];
    if (F32){
      const f32x4* xs = (const f32x4*)((const float*)x_ + (size_t)s    * DD + q * 16);
      const f32x4* xd = (const f32x4*)((const float*)x_ + (size_t)pD   * DD + q * 16);
      const f32x4* pe = (const f32x4*)((const float*)e_ + (size_t)eidx * DD + q * 16);
      #pragma unroll
      for (int j = 0; j < 4; ++j) pf[j]     = xs[j];
      #pragma unroll
      for (int j = 0; j < 4; ++j) pf[4 + j] = xd[j];
      #pragma unroll
      for (int j = 0; j < 4; ++j) pf[8 + j] = __builtin_nontemporal_load(pe + j);
    } else {
      const u16t* xs = (const u16t*)x_ + (size_t)s    * DD + q * 16;
      const u16t* xd = (const u16t*)x_ + (size_t)pD   * DD + q * 16;
      const u32x4* pe = (const u32x4*)((const u16t*)e_ + (size_t)eidx * DD + q * 16);
      pb[0] = *(const u32x4*)(xs); pb[1] = *(const u32x4*)(xs + 8);
      pb[2] = *(const u32x4*)(xd); pb[3] = *(const u32x4*)(xd + 8);
      pb[4] = __builtin_nontemporal_load(pe);
      pb[5] = __builtin_nontemporal_load(pe + 1);
    }
  };
  auto commit = [&](){
    if (q == 0) sDst[el] = pD;
    if (q == 1) sG[el]   = pG;
    u16t* row = sA + el * AS + q * 16;
    if (F32){
      #pragma unroll
      for (int sb = 0; sb < 3; ++sb){
        f32x4 a = pf[sb*4+0], b = pf[sb*4+1], c = pf[sb*4+2], d = pf[sb*4+3];
        uint4 o0 = { pk2(a[0], a[1]), pk2(a[2], a[3]), pk2(b[0], b[1]), pk2(b[2], b[3]) };
        uint4 o1 = { pk2(c[0], c[1]), pk2(c[2], c[3]), pk2(d[0], d[1]), pk2(d[2], d[3]) };
        *(uint4*)(row + sb * 64)     = o0;
        *(uint4*)(row + sb * 64 + 8) = o1;
      }
    } else {
      *(u32x4*)(row)       = pb[0]; *(u32x4*)(row + 8)   = pb[1];
      *(u32x4*)(row + 64)  = pb[2]; *(u32x4*)(row + 72)  = pb[3];
      *(u32x4*)(row + 128) = pb[4]; *(u32x4*)(row + 136) = pb[5];
    }
  };

  int tile = blockIdx.x;
  if (tile < ntiles) issue(tile);

  for (; tile < ntiles; tile += gridDim.x){
    const int base = tile * 64;

    // ---- commit staged tile, then fire next tile's gathers ----
    commit();
    {
      int tnext = tile + gridDim.x;
      if (tnext < ntiles) issue(tnext);
    }
    __syncthreads();

    // ---- fused layer 1 (K=192): edge full + attention [xs|xd|.] partial ----
    f32x4 accE[4][2], accA[4][2];
    #pragma unroll
    for (int rt = 0; rt < 4; ++rt){
      accE[rt][0] = vzero; accE[rt][1] = vzero;
      accA[rt][0] = vzero; accA[rt][1] = vzero;
    }
    #pragma unroll
    for (int kk = 0; kk < 6; ++kk){
      bf16x8 af[4], bwE[2];
      #pragma unroll
      for (int rt = 0; rt < 4; ++rt)
        af[rt] = ldfrag(&sA[(rt * 16 + l15) * AS + kk * 32 + quad * 8]);
      #pragma unroll
      for (int ct = 0; ct < 2; ++ct)
        bwE[ct] = ldfrag(&Wp1[((kk * HH + colbase + ct * 16 + l15) << 5) + quad * 8]);
      #pragma unroll
      for (int rt = 0; rt < 4; ++rt)
        #pragma unroll
        for (int ct = 0; ct < 2; ++ct)
          accE[rt][ct] = __builtin_amdgcn_mfma_f32_16x16x32_bf16(af[rt], bwE[ct], accE[rt][ct], 0, 0, 0);
      if (kk < 4){
        bf16x8 bwA[2];
        #pragma unroll
        for (int ct = 0; ct < 2; ++ct)
          bwA[ct] = ldfrag(&WpA1[((kk * HH + colbase + ct * 16 + l15) << 5) + quad * 8]);
        #pragma unroll
        for (int rt = 0; rt < 4; ++rt)
          #pragma unroll
          for (int ct = 0; ct < 2; ++ct)
            accA[rt][ct] = __builtin_amdgcn_mfma_f32_16x16x32_bf16(af[rt], bwA[ct], accA[rt][ct], 0, 0, 0);
      }
    }
    #pragma unroll
    for (int ct = 0; ct < 2; ++ct){
      const int col = colbase + ct * 16 + l15;
      #pragma unroll
      for (int rt = 0; rt < 4; ++rt)
        #pragma unroll
        for (int r = 0; r < 4; ++r){
          const int row = rt * 16 + quad * 4 + r;
          float h = fmaxf(accE[rt][ct][r] + U1[sG[row] * HH + col], 0.f);
          sH[row * HS + col] = f2bf(h);
        }
    }
    __syncthreads();

    // ---- edge MLP layer 2: [64x128] @ [128x64] -> e_new ----
    f32x4 acc2[4];
    #pragma unroll
    for (int rt = 0; rt < 4; ++rt) acc2[rt] = vzero;
    #pragma unroll
    for (int kk = 0; kk < 4; ++kk){
      bf16x8 af[4];
      #pragma unroll
      for (int rt = 0; rt < 4; ++rt)
        af[rt] = ldfrag(&sH[(rt * 16 + l15) * HS + kk * 32 + quad * 8]);
      bf16x8 bw = ldfrag(&Wp2[((kk * 64 + n0 + l15) << 5) + quad * 8]);
      #pragma unroll
      for (int rt = 0; rt < 4; ++rt)
        acc2[rt] = __builtin_amdgcn_mfma_f32_16x16x32_bf16(af[rt], bw, acc2[rt], 0, 0, 0);
    }
    float enew[4][4];
    {
      const int col = n0 + l15;
      #pragma unroll
      for (int rt = 0; rt < 4; ++rt)
        #pragma unroll
        for (int r = 0; r < 4; ++r){
          float v = acc2[rt][r] + bias2;
          enew[rt][r] = v;
          const int row = rt * 16 + quad * 4 + r;
          store1nt<F32>(d_out, OUT_E + (size_t)(base + row) * DD + col, v);
          sA[row * AS + 128 + col] = f2bf(v);   // e-slot <- e_new for attention
          atomicAdd(&sEagg[sG[row] * EAS + col], v);
        }
    }
    __syncthreads();

    // ---- attention finish: + e_new @ Wa1[128:192] rows ----
    #pragma unroll
    for (int kkl = 0; kkl < 2; ++kkl){
      bf16x8 af[4], bwA[2];
      #pragma unroll
      for (int rt = 0; rt < 4; ++rt)
        af[rt] = ldfrag(&sA[(rt * 16 + l15) * AS + 128 + kkl * 32 + quad * 8]);
      #pragma unroll
      for (int ct = 0; ct < 2; ++ct)
        bwA[ct] = ldfrag(&WpA1[(((4 + kkl) * HH + colbase + ct * 16 + l15) << 5) + quad * 8]);
      #pragma unroll
      for (int rt = 0; rt < 4; ++rt)
        #pragma unroll
        for (int ct = 0; ct < 2; ++ct)
          accA[rt][ct] = __builtin_amdgcn_mfma_f32_16x16x32_bf16(af[rt], bwA[ct], accA[rt][ct], 0, 0, 0);
    }
    #pragma unroll
    for (int ct = 0; ct < 2; ++ct){
      const int col = colbase + ct * 16 + l15;
      #pragma unroll
      for (int rt = 0; rt < 4; ++rt)
        #pragma unroll
        for (int r = 0; r < 4; ++r){
          const int row = rt * 16 + quad * 4 + r;
          float h = fmaxf(accA[rt][ct][r] + UA1[sG[row] * HH + col], 0.f);
          sH[row * HS + col] = f2bf(h);
        }
    }
    __syncthreads();

    // ---- attention layer 2 -> sigmoid -> scatter e_new*a into agg[dst] ----
    f32x4 acc4[4];
    #pragma unroll
    for (int rt = 0; rt < 4; ++rt) acc4[rt] = vzero;
    #pragma unroll
    for (int kk = 0; kk < 4; ++kk){
      bf16x8 af[4];
      #pragma unroll
      for (int rt = 0; rt < 4; ++rt)
        af[rt] = ldfrag(&sH[(rt * 16 + l15) * HS + kk * 32 + quad * 8]);
      bf16x8 bw = ldfrag(&WpA2[((kk * 64 + n0 + l15) << 5) + quad * 8]);
      #pragma unroll
      for (int rt = 0; rt < 4; ++rt)
        acc4[rt] = __builtin_amdgcn_mfma_f32_16x16x32_bf16(af[rt], bw, acc4[rt], 0, 0, 0);
    }
    {
      const int col = n0 + l15;
      #pragma unroll
      for (int rt = 0; rt < 4; ++rt)
        #pragma unroll
        for (int r = 0; r < 4; ++r){
          float sv = acc4[rt][r] + biasA2;
          float av = 1.0f / (1.0f + __expf(-sv));
          const int row = rt * 16 + quad * 4 + r;
          atomicAdd(&agg[(size_t)sDst[row] * DD + col], enew[rt][r] * av);
        }
    }
    __syncthreads();   // protect sA/sH/sDst/sG before next tile's commit
  }

  // flush per-block edge_agg partial
  for (int i = tid; i < NG * DD; i += 256)
    atomicAdd(&edge_agg[i], sEagg[(i >> 6) * EAS + (i & 63)]);
}

__global__ __launch_bounds__(256) void node_kernel(
  const void* __restrict__ x, const float* __restrict__ agg,
  const int* __restrict__ batch,
  const u16t* __restrict__ WpN1, const float* __restrict__ UN1,
  const u16t* __restrict__ WpN2, const void* __restrict__ bn2,
  void* __restrict__ d_out, float* __restrict__ node_agg, const int* __restrict__ flag)
{
  __shared__ u16t  sA[64 * NS];
  __shared__ u16t  sH[64 * HS];
  __shared__ float sNagg[NG * 72];
  __shared__ int   sGn[64];

  const bool f32 = (*flag != 0);
  const int tid  = threadIdx.x;
  const int wave = tid >> 6;
  const int lane = tid & 63;
  const int l15  = lane & 15;
  const int quad = lane >> 4;
  const int base = blockIdx.x * 64;

  for (int i = tid; i < NG * 72; i += 256) sNagg[i] = 0.f;

  // ---- stage [x | agg], 64 x 128 bf16 (u folded into UN1) ----
  {
    const int el = tid >> 2;
    const int q  = tid & 3;
    int n  = base + el;
    int nc = n < NN ? n : (NN - 1);
    int g  = batch[nc];
    if (q == 0) sGn[el] = g;
    u16t* row = sA + el * NS + q * 16;
    stage16(row,      x,   (size_t)nc * DD + q * 16, f32);
    stage16(row + 64, agg, (size_t)nc * DD + q * 16, true);
  }
  __syncthreads();

  const f32x4 vzero = {0.f, 0.f, 0.f, 0.f};
  const int colbase = wave * 32;
  const int n0      = wave * 16;

  // ---- node MLP layer 1: K=128 ----
  f32x4 acc[4][2];
  #pragma unroll
  for (int rt = 0; rt < 4; ++rt){ acc[rt][0] = vzero; acc[rt][1] = vzero; }
  #pragma unroll
  for (int kk = 0; kk < 4; ++kk){
    bf16x8 af[4], bw[2];
    #pragma unroll
    for (int rt = 0; rt < 4; ++rt)
      af[rt] = ldfrag(&sA[(rt * 16 + l15) * NS + kk * 32 + quad * 8]);
    #pragma unroll
    for (int ct = 0; ct < 2; ++ct)
      bw[ct] = ldfrag(&WpN1[((kk * HH + colbase + ct * 16 + l15) << 5) + quad * 8]);
    #pragma unroll
    for (int rt = 0; rt < 4; ++rt)
      #pragma unroll
      for (int ct = 0; ct < 2; ++ct)
        acc[rt][ct] = __builtin_amdgcn_mfma_f32_16x16x32_bf16(af[rt], bw[ct], acc[rt][ct], 0, 0, 0);
  }
  #pragma unroll
  for (int ct = 0; ct < 2; ++ct){
    const int col = colbase + ct * 16 + l15;
    #pragma unroll
    for (int rt = 0; rt < 4; ++rt)
      #pragma unroll
      for (int r = 0; r < 4; ++r){
        const int row = rt * 16 + quad * 4 + r;
        float h = fmaxf(acc[rt][ct][r] + UN1[sGn[row] * HH + col], 0.f);
        sH[row * HS + col] = f2bf(h);
      }
  }
  __syncthreads();

  // ---- node MLP layer 2 -> x_new ----
  f32x4 acc2[4];
  #pragma unroll
  for (int rt = 0; rt < 4; ++rt) acc2[rt] = vzero;
  #pragma unroll
  for (int kk = 0; kk < 4; ++kk){
    bf16x8 af[4];
    #pragma unroll
    for (int rt = 0; rt < 4; ++rt)
      af[rt] = ldfrag(&sH[(rt * 16 + l15) * HS + kk * 32 + quad * 8]);
    bf16x8 bw = ldfrag(&WpN2[((kk * 64 + n0 + l15) << 5) + quad * 8]);
    #pragma unroll
    for (int rt = 0; rt < 4; ++rt)
      acc2[rt] = __builtin_amdgcn_mfma_f32_16x16x32_bf16(af[rt], bw, acc2[rt], 0, 0, 0);
  }
  {
    const int col = n0 + l15;
    const float bias = ldb(bn2, col, f32);
    #pragma unroll
    for (int rt = 0; rt < 4; ++rt)
      #pragma unroll
      for (int r = 0; r < 4; ++r){
        const int row = rt * 16 + quad * 4 + r;
        const int n = base + row;
        if (n < NN){
          float v = acc2[rt][r] + bias;
          store1nt_rt(d_out, (size_t)n * DD + col, v, f32);
          atomicAdd(&sNagg[sGn[row] * 72 + col], v);
        }
      }
  }
  __syncthreads();
  for (int i = tid; i < NG * DD; i += 256)
    atomicAdd(&node_agg[i], sNagg[(i >> 6) * 72 + (i & 63)]);
}

__global__ __launch_bounds__(256) void global_kernel(
  const void* __restrict__ u, const float* __restrict__ node_agg, const float* __restrict__ edge_agg,
  const void* __restrict__ Wg1, const void* __restrict__ bg1,
  const void* __restrict__ Wg2, const void* __restrict__ bg2,
  void* __restrict__ d_out, const int* __restrict__ flag)
{
  __shared__ float sIn[NG * 192];
  __shared__ float sHg[NG * HH];
  const bool f32 = (*flag != 0);
  const size_t OUT_U = (size_t)NN * DD + (size_t)NE * DD;
  const int tid = threadIdx.x;
  for (int i = tid; i < NG * 192; i += 256){
    int g = i / 192, c = i - g * 192;
    float v;
    if      (c <  64) v = ldb(u, g * 64 + c, f32);
    else if (c < 128) v = node_agg[g * 64 + (c - 64)];
    else              v = edge_agg[g * 64 + (c - 128)];
    sIn[i] = v;
  }
  __syncthreads();
  for (int i = tid; i < NG * HH; i += 256){
    int g = i >> 7, j = i & 127;
    float s = ldb(bg1, j, f32);
    for (int k = 0; k < 192; ++k)
      s += sIn[g * 192 + k] * ldb(Wg1, k * 128 + j, f32);
    sHg[i] = fmaxf(s, 0.f);
  }
  __syncthreads();
  for (int i = tid; i < NG * DD; i += 256){
    int g = i >> 6, j = i & 63;
    float s = ldb(bg2, j, f32);
    for (int k = 0; k < 128; ++k)
      s += sHg[g * 128 + k] * ldb(Wg2, k * 64 + j, f32);
    store1nt_rt(d_out, OUT_U + i, s, f32);
  }
}

extern "C" void kernel_launch(void* const* d_in, const int* in_sizes, int n_in,
                              void* d_out, int out_size, void* d_ws, size_t ws_size,
                              hipStream_t stream)
{
  const void* x     = d_in[0];
  const int*  ei    = (const int*)d_in[1];
  const void* e     = d_in[2];
  const void* u     = d_in[3];
  const int*  batch = (const int*)d_in[4];
  const void* We1 = d_in[5];
  const void* be1 = d_in[6];
  const void* We2 = d_in[7];
  const void* be2 = d_in[8];
  const void* Wa1 = d_in[9];
  const void* ba1 = d_in[10];
  const void* Wa2 = d_in[11];
  const void* ba2 = d_in[12];
  const void* Wn1 = d_in[13];
  const void* bn1 = d_in[14];
  const void* Wn2 = d_in[15];
  const void* bn2 = d_in[16];
  const void* Wg1 = d_in[17];
  const void* bg1 = d_in[18];
  const void* Wg2 = d_in[19];
  const void* bg2 = d_in[20];

  // workspace: [flag 16B][agg NN*DD][edge_agg][node_agg][U1][UA1][UN1][packed W]
  int*   flag     = (int*)d_ws;
  float* agg      = (float*)((char*)d_ws + 16);
  float* edge_agg = agg + (size_t)NN * DD;
  float* node_agg = edge_agg + NG * DD;
  float* U1  = node_agg + NG * DD;
  float* UA1 = U1  + NG * HH;
  float* UN1 = UA1 + NG * HH;
  u16t*  wp    = (u16t*)(UN1 + NG * HH);
  u16t*  Wp_e1 = wp; wp += 192 * 128;
  u16t*  Wp_e2 = wp; wp += 128 * 64;
  u16t*  Wp_a1 = wp; wp += 192 * 128;
  u16t*  Wp_a2 = wp; wp += 128 * 64;
  u16t*  Wp_n1 = wp; wp += 128 * 128;
  u16t*  Wp_n2 = wp; wp += 128 * 64;

  detect_kernel<<<1, 64, 0, stream>>>(x, flag);
  (void)hipMemsetAsync(agg, 0, ((size_t)NN * DD + 2 * NG * DD) * sizeof(float), stream);

  ufold_kernel<<<(3 * NG * HH + 255) / 256, 256, 0, stream>>>(
      u, We1, be1, Wa1, ba1, Wn1, bn1, U1, UA1, UN1, flag);

  repack_kernel<<<(192 * 128 + 255) / 256, 256, 0, stream>>>(We1, Wp_e1, 192, 128, flag);
  repack_kernel<<<(128 * 64  + 255) / 256, 256, 0, stream>>>(We2, Wp_e2, 128, 64, flag);
  repack_kernel<<<(192 * 128 + 255) / 256, 256, 0, stream>>>(Wa1, Wp_a1, 192, 128, flag);
  repack_kernel<<<(128 * 64  + 255) / 256, 256, 0, stream>>>(Wa2, Wp_a2, 128, 64, flag);
  repack_kernel<<<(128 * 128 + 255) / 256, 256, 0, stream>>>(Wn1, Wp_n1, 128, 128, flag);
  repack_kernel<<<(128 * 64  + 255) / 256, 256, 0, stream>>>(Wn2, Wp_n2, 128, 64, flag);

  // dual-instantiation dispatch: each checks the device flag, wrong one exits
  edge_kernel<true><<<1536, 256, 0, stream>>>(x, ei, e, batch,
      Wp_e1, Wp_a1, Wp_e2, be2, Wp_a2, ba2, U1, UA1,
      d_out, agg, edge_agg, flag, NE / 64);
  edge_kernel<false><<<1536, 256, 0, stream>>>(x, ei, e, batch,
      Wp_e1, Wp_a1, Wp_e2, be2, Wp_a2, ba2, U1, UA1,
      d_out, agg, edge_agg, flag, NE / 64);

  node_kernel<<<(NN + 63) / 64, 256, 0, stream>>>(x, agg, batch,
      Wp_n1, UN1, Wp_n2, bn2, d_out, node_agg, flag);

  global_kernel<<<1, 256, 0, stream>>>(u, node_agg, edge_agg,
      Wg1, bg1, Wg2, bg2, d_out, flag);
}